// Round 12
// baseline (540.820 us; speedup 1.0000x reference)
//
#include <hip/hip_runtime.h>
#include <hip/hip_bf16.h>

// ============================================================
// 2-layer GCN. Per layer:
//   g = (X @ W) * dinv[row]   -- MFMA bf16 2-pass split
//      (x=x_hi+x_lo, W bf16; x_hi*W + x_lo*W, fp32 accum.
//       W-bf16 error ~1e-4 RMS << g bf16-store error ~2e-3)
//   out_i = relu(dinv_i * (sum_{e:dst=i} g[src_e] + g_i) + b)
// R12: 64KB W-LDS (2 blocks/CU), gemm2 single-pass 16KB LDS,
// cursor pre-init in scan (fill = 1 atomic), fill grid 2048.
// ============================================================

typedef __attribute__((ext_vector_type(8))) short bf16x8;
typedef __attribute__((ext_vector_type(4))) float f32x4;

__device__ inline unsigned short f2bf(float f) {        // RNE
    unsigned u = __float_as_uint(f);
    u = (u + 0x7fff + ((u >> 16) & 1)) >> 16;
    return (unsigned short)u;
}
__device__ inline float bf2f(unsigned short h) {
    return __uint_as_float(((unsigned)h) << 16);
}
__device__ inline float bflo(unsigned u) { return __uint_as_float(u << 16); }
__device__ inline float bfhi(unsigned u) { return __uint_as_float(u & 0xffff0000u); }
__device__ inline unsigned pack_bf16_2(float lo, float hi) {
    return (unsigned)f2bf(lo) | ((unsigned)f2bf(hi) << 16);
}
__device__ inline unsigned cvtpk(float a, float b) {    // dst = {bf16(b),bf16(a)}
    unsigned r;
    asm("v_cvt_pk_bf16_f32 %0, %1, %2" : "=v"(r) : "v"(a), "v"(b));
    return r;
}
// split 8 fp32 -> hi/lo bf16x8 (lo = exact residual of hi)
__device__ inline void split8(float4 qa, float4 qb, bf16x8& h8, bf16x8& l8) {
    float v0=qa.x, v1=qa.y, v2=qa.z, v3=qa.w, v4=qb.x, v5=qb.y, v6=qb.z, v7=qb.w;
    unsigned h0=cvtpk(v0,v1), h1=cvtpk(v2,v3), h2=cvtpk(v4,v5), h3=cvtpk(v6,v7);
    float r0=v0-bflo(h0), r1=v1-bfhi(h0), r2=v2-bflo(h1), r3=v3-bfhi(h1);
    float r4=v4-bflo(h2), r5=v5-bfhi(h2), r6=v6-bflo(h3), r7=v7-bfhi(h3);
    unsigned l0=cvtpk(r0,r1), l1=cvtpk(r2,r3), l2=cvtpk(r4,r5), l3=cvtpk(r6,r7);
    uint4 H = make_uint4(h0,h1,h2,h3), L = make_uint4(l0,l1,l2,l3);
    h8 = __builtin_bit_cast(bf16x8, H);
    l8 = __builtin_bit_cast(bf16x8, L);
}

// ---------- prep: W1,W2 -> bf16 transposed [N][K] + degree histogram ----------
__global__ void prep_kernel(const int* __restrict__ dst, int* __restrict__ deg, int E,
        const float* __restrict__ W1, unsigned short* __restrict__ w1t,
        const float* __restrict__ W2, unsigned short* __restrict__ w2t) {
    const int W1B = (256 * 128) / 256;   // 128 blocks
    const int W2B = (128 * 64) / 256;    // 32 blocks
    int b = blockIdx.x;
    if (b < W1B) {                        // W1 [K=256][N=128] -> [n][k] bf16
        int idx = b * 256 + threadIdx.x;
        int k = idx >> 7, n = idx & 127;
        w1t[(size_t)n * 256 + k] = f2bf(W1[idx]);
    } else if (b < W1B + W2B) {           // W2 [K=128][N=64] -> [n][k] bf16
        int idx = (b - W1B) * 256 + threadIdx.x;
        int k = idx >> 6, n = idx & 63;
        w2t[(size_t)n * 128 + k] = f2bf(W2[idx]);
    } else {                              // histogram
        int nb = gridDim.x - (W1B + W2B);
        int stride = nb * 256;
        for (int i = (b - W1B - W2B) * 256 + threadIdx.x; i < E; i += stride)
            atomicAdd(&deg[dst[i]], 1);
    }
}

// ---------- scan pass 1: per-4096-block sums; also dinv = 1/sqrt(deg+1) ----------
__global__ __launch_bounds__(1024) void scan_partial_kernel(const int* __restrict__ deg,
        int* __restrict__ psum, float* __restrict__ dinv, int n) {
    __shared__ int wsum[16];
    int tid = threadIdx.x, wave = tid >> 6, lane = tid & 63;
    int i0 = blockIdx.x * 4096 + tid * 4;
    int v0 = 0, v1 = 0, v2 = 0, v3 = 0;
    if (i0 + 3 < n) {
        int4 v = *(const int4*)(deg + i0);
        v0 = v.x; v1 = v.y; v2 = v.z; v3 = v.w;
    } else {
        if (i0 + 0 < n) v0 = deg[i0 + 0];
        if (i0 + 1 < n) v1 = deg[i0 + 1];
        if (i0 + 2 < n) v2 = deg[i0 + 2];
        if (i0 + 3 < n) v3 = deg[i0 + 3];
    }
    if (i0 + 0 < n) dinv[i0 + 0] = 1.0f / sqrtf((float)v0 + 1.0f);
    if (i0 + 1 < n) dinv[i0 + 1] = 1.0f / sqrtf((float)v1 + 1.0f);
    if (i0 + 2 < n) dinv[i0 + 2] = 1.0f / sqrtf((float)v2 + 1.0f);
    if (i0 + 3 < n) dinv[i0 + 3] = 1.0f / sqrtf((float)v3 + 1.0f);
    int s = v0 + v1 + v2 + v3;
    #pragma unroll
    for (int off = 1; off < 64; off <<= 1) s += __shfl_xor(s, off, 64);
    if (lane == 0) wsum[wave] = s;
    __syncthreads();
    if (tid == 0) {
        int t = 0;
        #pragma unroll
        for (int w = 0; w < 16; ++w) t += wsum[w];
        psum[blockIdx.x] = t;
    }
}

// ---------- scan pass 2: local scan + inline base; writes offs AND cursor ----------
__global__ __launch_bounds__(1024) void scan_local_kernel(const int* __restrict__ deg,
        const int* __restrict__ psum, int* __restrict__ offs, int* __restrict__ cursor,
        int n, int sb) {
    __shared__ int wsum[16];
    int tid = threadIdx.x, wave = tid >> 6, lane = tid & 63;
    int bid = blockIdx.x;
    int base = 0, total = 0;
    for (int w = 0; w < sb; ++w) {
        int t = psum[w];
        if (w < bid) base += t;
        total += t;
    }
    if (bid == 0 && tid == 0) offs[n] = total;

    int i0 = bid * 4096 + tid * 4;
    int v0 = 0, v1 = 0, v2 = 0, v3 = 0;
    if (i0 + 3 < n) {
        int4 v = *(const int4*)(deg + i0);
        v0 = v.x; v1 = v.y; v2 = v.z; v3 = v.w;
    } else {
        if (i0 + 0 < n) v0 = deg[i0 + 0];
        if (i0 + 1 < n) v1 = deg[i0 + 1];
        if (i0 + 2 < n) v2 = deg[i0 + 2];
        if (i0 + 3 < n) v3 = deg[i0 + 3];
    }
    int s = v0 + v1 + v2 + v3;
    int x = s;
    #pragma unroll
    for (int off = 1; off < 64; off <<= 1) {
        int y = __shfl_up(x, off, 64);
        if (lane >= off) x += y;
    }
    if (lane == 63) wsum[wave] = x;
    __syncthreads();
    int wbase = 0;
    #pragma unroll
    for (int w = 0; w < 16; ++w)
        if (w < wave) wbase += wsum[w];
    int ex = base + wbase + (x - s);
    if (i0 + 0 < n) { offs[i0 + 0] = ex;                cursor[i0 + 0] = ex; }
    if (i0 + 1 < n) { offs[i0 + 1] = ex + v0;           cursor[i0 + 1] = ex + v0; }
    if (i0 + 2 < n) { offs[i0 + 2] = ex + v0 + v1;      cursor[i0 + 2] = ex + v0 + v1; }
    if (i0 + 3 < n) { offs[i0 + 3] = ex + v0 + v1 + v2; cursor[i0 + 3] = ex + v0 + v1 + v2; }
}

// ---------- CSR bucket fill: single atomic (cursor pre-init to offs) ----------
__global__ void fill_kernel(const int* __restrict__ src, const int* __restrict__ dst,
        int* __restrict__ cursor, int* __restrict__ csr, int E) {
    int stride = gridDim.x * blockDim.x;
    for (int i = blockIdx.x * blockDim.x + threadIdx.x; i < E; i += stride) {
        int pos = atomicAdd(&cursor[dst[i]], 1);
        csr[pos] = src[i];
    }
}

// ---------- layer-1 GEMM: W1 bf16 in 64KB LDS, 2-pass x-split, barrier-free ----------
// 1024 thr = 16 waves (4 rowg x 4 colq); wave = 64 rows x 32 cols; 2 blocks/CU.
__global__ __launch_bounds__(1024, 4) void gemm1_kernel(const float* __restrict__ X,
        const unsigned short* __restrict__ Wt,
        const float* __restrict__ dinv, unsigned short* __restrict__ G, int M) {
    __shared__ uint4 LW[4096];           // 64KB  (32 kblk x 128 n)
    const int tid = threadIdx.x;
    {
        const uint4* gw = (const uint4*)Wt;
        #pragma unroll
        for (int j = 0; j < 4; ++j) {
            int i = tid + j * 1024;
            int kb = i >> 7, n = i & 127;
            LW[i] = gw[n * 32 + kb];
        }
    }
    __syncthreads();                     // only barrier; W read-only after

    const int wv = tid >> 6, ln = tid & 63;
    const int l16 = ln & 15, kseg = ln >> 4;
    const int wr = wv >> 2, wc = wv & 3;
    const int r0 = blockIdx.x * 256 + wr * 64;

    const float* pA[4];
    #pragma unroll
    for (int tr = 0; tr < 4; ++tr) {
        int rr = r0 + tr * 16 + l16;
        if (rr >= M) rr = M - 1;
        pA[tr] = X + (size_t)rr * 256 + kseg * 8;
    }

    f32x4 acc[4][2];
    #pragma unroll
    for (int a = 0; a < 4; ++a)
        #pragma unroll
        for (int b = 0; b < 2; ++b) acc[a][b] = 0;

    for (int k0 = 0; k0 < 256; k0 += 32) {           // 8 iters
        const int kb4 = (k0 >> 3) + kseg;
        bf16x8 bh[2];
        #pragma unroll
        for (int tc = 0; tc < 2; ++tc)
            bh[tc] = __builtin_bit_cast(bf16x8, LW[kb4 * 128 + wc * 32 + tc * 16 + l16]);
        #pragma unroll
        for (int tr = 0; tr < 4; ++tr) {
            float4 qa = *(const float4*)(pA[tr] + k0);
            float4 qb = *(const float4*)(pA[tr] + k0 + 4);
            bf16x8 ah, al;
            split8(qa, qb, ah, al);
            #pragma unroll
            for (int tc = 0; tc < 2; ++tc) {
                acc[tr][tc] = __builtin_amdgcn_mfma_f32_16x16x32_bf16(ah, bh[tc], acc[tr][tc], 0, 0, 0);
                acc[tr][tc] = __builtin_amdgcn_mfma_f32_16x16x32_bf16(al, bh[tc], acc[tr][tc], 0, 0, 0);
            }
        }
    }

    #pragma unroll
    for (int tr = 0; tr < 4; ++tr) {
        int rbase = r0 + tr * 16 + (ln >> 4) * 4;
        #pragma unroll
        for (int r = 0; r < 4; ++r) {
            int row = rbase + r;
            if (row < M) {
                float dv = dinv[row];
                #pragma unroll
                for (int tc = 0; tc < 2; ++tc)
                    G[(size_t)row * 128 + wc * 32 + tc * 16 + l16] =
                        f2bf(acc[tr][tc][r] * dv);
            }
        }
    }
}

// ---------- layer-2 GEMM: W2 bf16 in 16KB LDS, A = bf16 h1, single pass ----------
// 1024 thr = 16 waves (8 rowg x 2 colh); wave = 64 rows x 32 cols.
__global__ __launch_bounds__(1024, 4) void gemm2_kernel(const unsigned short* __restrict__ H,
        const unsigned short* __restrict__ Wt,
        const float* __restrict__ dinv, unsigned short* __restrict__ G, int M) {
    __shared__ uint4 LW[1024];           // 16KB (16 kblk x 64 n)
    const int tid = threadIdx.x;
    {
        int kb = tid >> 6, n = tid & 63;
        LW[tid] = ((const uint4*)Wt)[n * 16 + kb];
    }
    __syncthreads();

    const int wv = tid >> 6, ln = tid & 63;
    const int l16 = ln & 15, kseg = ln >> 4;
    const int wr = wv >> 1, wc = wv & 1;
    const int r0 = blockIdx.x * 512 + wr * 64;

    const unsigned short* pA[4];
    #pragma unroll
    for (int tr = 0; tr < 4; ++tr) {
        int rr = r0 + tr * 16 + l16;
        if (rr >= M) rr = M - 1;
        pA[tr] = H + (size_t)rr * 128 + kseg * 8;
    }

    f32x4 acc[4][2];
    #pragma unroll
    for (int a = 0; a < 4; ++a)
        #pragma unroll
        for (int b = 0; b < 2; ++b) acc[a][b] = 0;

    for (int k0 = 0; k0 < 128; k0 += 32) {           // 4 iters
        const int kb4 = (k0 >> 3) + kseg;
        bf16x8 bh[2];
        #pragma unroll
        for (int tc = 0; tc < 2; ++tc)
            bh[tc] = __builtin_bit_cast(bf16x8, LW[kb4 * 64 + wc * 32 + tc * 16 + l16]);
        #pragma unroll
        for (int tr = 0; tr < 4; ++tr) {
            bf16x8 a0 = *(const bf16x8*)(pA[tr] + k0);
            #pragma unroll
            for (int tc = 0; tc < 2; ++tc)
                acc[tr][tc] = __builtin_amdgcn_mfma_f32_16x16x32_bf16(a0, bh[tc], acc[tr][tc], 0, 0, 0);
        }
    }

    #pragma unroll
    for (int tr = 0; tr < 4; ++tr) {
        int rbase = r0 + tr * 16 + (ln >> 4) * 4;
        #pragma unroll
        for (int r = 0; r < 4; ++r) {
            int row = rbase + r;
            if (row < M) {
                float dv = dinv[row];
                #pragma unroll
                for (int tc = 0; tc < 2; ++tc)
                    G[(size_t)row * 64 + wc * 32 + tc * 16 + l16] =
                        f2bf(acc[tr][tc][r] * dv);
            }
        }
    }
}

// ---------- aggregate, F=128, bf16 in / bf16 packed out, ILP=8 ----------
__global__ __launch_bounds__(256) void aggregate128_kernel(const unsigned* __restrict__ G,
        const int* __restrict__ csr, const int* __restrict__ offs,
        const float* __restrict__ dinv, const float* __restrict__ bias,
        unsigned* __restrict__ out, int n) {
    int wave = threadIdx.x >> 6, lane = threadIdx.x & 63;
    int node = blockIdx.x * 4 + wave;
    if (node >= n) return;
    int beg = offs[node], end = offs[node + 1];

    unsigned u = G[(size_t)node * 64 + lane];          // self loop
    float a0 = bflo(u), a1 = bfhi(u);
    int e = beg;
    for (; e + 8 <= end; e += 8) {                     // 8 rows in flight
        unsigned uu[8];
        #pragma unroll
        for (int j = 0; j < 8; ++j) uu[j] = G[(size_t)csr[e + j] * 64 + lane];
        #pragma unroll
        for (int j = 0; j < 8; ++j) { a0 += bflo(uu[j]); a1 += bfhi(uu[j]); }
    }
    for (; e + 4 <= end; e += 4) {
        unsigned uu[4];
        #pragma unroll
        for (int j = 0; j < 4; ++j) uu[j] = G[(size_t)csr[e + j] * 64 + lane];
        #pragma unroll
        for (int j = 0; j < 4; ++j) { a0 += bflo(uu[j]); a1 += bfhi(uu[j]); }
    }
    for (; e < end; ++e) {
        unsigned u0 = G[(size_t)csr[e] * 64 + lane];
        a0 += bflo(u0);
        a1 += bfhi(u0);
    }
    float di = dinv[node];
    float rx = fmaxf(fmaf(a0, di, bias[lane * 2 + 0]), 0.0f);
    float ry = fmaxf(fmaf(a1, di, bias[lane * 2 + 1]), 0.0f);
    out[(size_t)node * 64 + lane] = pack_bf16_2(rx, ry);
}

// ---------- aggregate, F=64, bf16 in / fp32 out, split-wave ----------
__global__ __launch_bounds__(256) void aggregate64_kernel(const unsigned* __restrict__ G,
        const int* __restrict__ csr, const int* __restrict__ offs,
        const float* __restrict__ dinv, const float* __restrict__ bias,
        float* __restrict__ out, int n) {
    int wave = threadIdx.x >> 6, lane = threadIdx.x & 63;
    int node = blockIdx.x * 4 + wave;
    if (node >= n) return;
    int beg = offs[node], end = offs[node + 1];
    int half = lane >> 5, col = lane & 31;

    float a0 = 0.0f, a1 = 0.0f;
    if (half == 0) {                                   // self loop on low half
        unsigned u = G[(size_t)node * 32 + col];
        a0 = bflo(u); a1 = bfhi(u);
    }
    int e = beg;
    for (; e + 8 <= end; e += 8) {                     // 8 edges/iter (4 per half)
        unsigned uu[4];
        #pragma unroll
        for (int j = 0; j < 4; ++j) uu[j] = G[(size_t)csr[e + 2 * j + half] * 32 + col];
        #pragma unroll
        for (int j = 0; j < 4; ++j) { a0 += bflo(uu[j]); a1 += bfhi(uu[j]); }
    }
    for (; e + 2 <= end; e += 2) {
        unsigned uA = G[(size_t)csr[e + half] * 32 + col];
        a0 += bflo(uA);
        a1 += bfhi(uA);
    }
    if (e < end && half == 0) {
        unsigned uA = G[(size_t)csr[e] * 32 + col];
        a0 += bflo(uA);
        a1 += bfhi(uA);
    }
    a0 += __shfl_down(a0, 32, 64);
    a1 += __shfl_down(a1, 32, 64);
    if (half == 0) {
        float di = dinv[node];
        float2 r;
        r.x = fmaxf(fmaf(a0, di, bias[col * 2 + 0]), 0.0f);
        r.y = fmaxf(fmaf(a1, di, bias[col * 2 + 1]), 0.0f);
        ((float2*)(out + (size_t)node * 64))[col] = r;
    }
}

extern "C" void kernel_launch(void* const* d_in, const int* in_sizes, int n_in,
                              void* d_out, int out_size, void* d_ws, size_t ws_size,
                              hipStream_t stream) {
    const float* x  = (const float*)d_in[0];
    const float* W1 = (const float*)d_in[1];
    const float* b1 = (const float*)d_in[2];
    const float* W2 = (const float*)d_in[3];
    const float* b2 = (const float*)d_in[4];
    const int* edge = (const int*)d_in[5];

    const int IN = 256, H1 = 128, H2 = 64;
    const int E = in_sizes[5] / 2;
    const int N = in_sizes[0] / IN;
    const int* srcp = edge;
    const int* dstp = edge + E;

    char* ws = (char*)d_ws;
    auto alignup = [](size_t v) { return (v + 255) & ~(size_t)255; };
    size_t off = 0;
    size_t degSz = alignup((size_t)N * 4);
    int*            deg    = (int*)(ws + off);            off += degSz;
    int*            cursor = (int*)(ws + off);            off += degSz;
    int*            offs   = (int*)(ws + off);            off += alignup(((size_t)N + 1) * 4);
    float*          dinv   = (float*)(ws + off);          off += degSz;
    int*            psum   = (int*)(ws + off);            off += alignup(64 * 4);
    int*            csr    = (int*)(ws + off);            off += alignup((size_t)E * 4);
    unsigned short* wt1    = (unsigned short*)(ws + off); off += alignup((size_t)IN * H1 * 2);
    unsigned short* wt2    = (unsigned short*)(ws + off); off += alignup((size_t)H1 * H2 * 2);
    unsigned short* g1     = (unsigned short*)(ws + off); off += alignup((size_t)N * H1 * 2);
    unsigned*       h1b    = (unsigned*)(ws + off);       off += alignup((size_t)N * (H1 / 2) * 4);
    unsigned short* g2     = g1;                          // g1 dead after aggregate1

    hipMemsetAsync(deg, 0, degSz, stream);       // cursor init'd by scan_local

    int sb = (N + 4095) / 4096;                  // 25 blocks (<=64 required)

    prep_kernel<<<160 + 2048, 256, 0, stream>>>(dstp, deg, E, W1, wt1, W2, wt2);
    scan_partial_kernel<<<sb, 1024, 0, stream>>>(deg, psum, dinv, N);
    scan_local_kernel<<<sb, 1024, 0, stream>>>(deg, psum, offs, cursor, N, sb);
    fill_kernel<<<2048, 256, 0, stream>>>(srcp, dstp, cursor, csr, E);

    int g1grid = (N + 255) / 256;                // 391 blocks, 256 rows each
    int g2grid = (N + 511) / 512;                // 196 blocks, 512 rows each
    int agrid  = (N + 3) / 4;

    gemm1_kernel<<<g1grid, 1024, 0, stream>>>(x, wt1, dinv, g1, N);
    aggregate128_kernel<<<agrid, 256, 0, stream>>>((const unsigned*)g1, csr, offs,
                                                   dinv, b1, h1b, N);
    gemm2_kernel<<<g2grid, 1024, 0, stream>>>((const unsigned short*)h1b, wt2,
                                              dinv, g2, N);
    aggregate64_kernel<<<agrid, 256, 0, stream>>>((const unsigned*)g2, csr, offs,
                                                  dinv, b2, (float*)d_out, N);
}